// Round 2
// baseline (1040.856 us; speedup 1.0000x reference)
//
#include <hip/hip_runtime.h>
#include <string.h>

// LSTM B=4096, L=512, M=H=17. 256 blocks x 16 batch, 4 waves (1/SIMD).
// Waves 0-2: gate tile T=w; wave 3: tiles 3 and 4 (j=16). Per-step barrier is
// lgkmcnt-only (asm) so global stores never drain at the barrier.
// h exchanged via kappa-permuted LDS planes (write b16, read 4x b32, 2-way banks).
// Wave 0 runs a 4-deep x pipeline: global load -> bf16 frag -> LDS ring + passthrough.

typedef __attribute__((ext_vector_type(8))) short bf16x8;
typedef __attribute__((ext_vector_type(4))) float f32x4;
typedef __attribute__((ext_vector_type(4))) int i32x4;

namespace {
constexpr int B_TOT = 4096, L_SEQ = 512, NF = 17;
constexpr int OUT_H = B_TOT * L_SEQ * NF;
constexpr int OUT_C = OUT_H + B_TOT * NF;
constexpr int OUT_X = OUT_C + B_TOT * NF;
}

__device__ __forceinline__ float sigm(float v) {
  return __builtin_amdgcn_rcpf(1.f + __expf(-v));
}
__device__ __forceinline__ float tanh_f(float v) {
  float e = __expf(2.f * v);                       // inf -> rcp -> 0: safe
  return 1.f - 2.f * __builtin_amdgcn_rcpf(e + 1.f);
}
__device__ __forceinline__ unsigned pack_bf(float a, float b) {  // (lo=a, hi=b), round-half-up
  return ((__float_as_uint(a) + 0x8000u) >> 16) | ((__float_as_uint(b) + 0x8000u) & 0xffff0000u);
}
__device__ __forceinline__ unsigned short bf1(float a) {
  return (unsigned short)((__float_as_uint(a) + 0x8000u) >> 16);
}

__global__ void __launch_bounds__(256) lstm_kernel(
    const float* __restrict__ x, const float* __restrict__ W_ih,
    const float* __restrict__ W_hh, const float* __restrict__ b_ih,
    const float* __restrict__ b_hh, float* __restrict__ out)
{
  // hx: bf16x2 dwords, [buf][plane u][bb*4 + swz(e,bb)], plane stride 65 kills
  // write-side bank aliasing. kappa slot (q,2u+s) carries h[8q+u+4s].
  __shared__ unsigned hx[2][4][65];
  __shared__ unsigned xs[4][4][64];   // x frags: [slot t&3][dword d][lane]

  const int tid  = threadIdx.x;
  const int lane = tid & 63;
  const int w    = tid >> 6;          // wave id
  const int bb   = lane & 15;         // batch col / A row
  const int q    = lane >> 4;         // k-octet / C row-quad
  const int b0   = blockIdx.x * 16;

  for (int u = tid; u < 2 * 4 * 65; u += 256) ((unsigned*)hx)[u] = 0;

  // ---- per-wave weight fragments (kappa order), tiles: tt0 -> T=w, tt1 -> T=4 (w3 only)
  bf16x8 a0[2], a1[2]; f32x4 bias[2];
  #pragma unroll
  for (int tt = 0; tt < 2; ++tt) {
    const int T = tt ? 4 : w;
    unsigned d0[4], d1[4];
    const int R = 16 * T + bb, j = R >> 2, ty = R & 3;
    const bool vr = (j <= 16);
    #pragma unroll
    for (int u = 0; u < 4; ++u) {
      const int k0 = 8 * q + u, k1 = k0 + 4;
      float wa0 = (vr && k0 < NF) ? W_ih[(ty * NF + j) * NF + k0] : 0.f;
      float wa1 = (vr && k1 < NF) ? W_ih[(ty * NF + j) * NF + k1] : 0.f;
      float wb0 = (vr && k0 < NF) ? W_hh[(ty * NF + j) * NF + k0] : 0.f;
      float wb1 = (vr && k1 < NF) ? W_hh[(ty * NF + j) * NF + k1] : 0.f;
      d0[u] = pack_bf(wa0, wa1);
      d1[u] = pack_bf(wb0, wb1);
    }
    a0[tt] = __builtin_bit_cast(bf16x8, i32x4{(int)d0[0], (int)d0[1], (int)d0[2], (int)d0[3]});
    a1[tt] = __builtin_bit_cast(bf16x8, i32x4{(int)d1[0], (int)d1[1], (int)d1[2], (int)d1[3]});
    f32x4 bv;
    #pragma unroll
    for (int r = 0; r < 4; ++r) {
      const int Rc = 16 * T + 4 * q + r, jc = Rc >> 2, tyc = Rc & 3;
      bv[r] = (jc <= 16) ? (b_ih[tyc * NF + jc] + b_hh[tyc * NF + jc]) : 0.f;
    }
    bias[tt] = bv;
  }

  // ---- x pipeline (wave 0): xb[slot t&3][8 floats], 3-step flight
  float xb[4][8];
  const int xoff = (b0 + bb) * L_SEQ * NF + 8 * q;   // + t*NF

  auto load_x = [&](int slot, int t) {
    const float* p = x + xoff + t * NF;
    if (q < 2) {
      memcpy(&xb[slot][0], p, 16);
      memcpy(&xb[slot][4], p + 4, 16);
    } else if (q == 2) {
      xb[slot][0] = p[0];
      #pragma unroll
      for (int e = 1; e < 8; ++e) xb[slot][e] = 0.f;
    } else {
      #pragma unroll
      for (int e = 0; e < 8; ++e) xb[slot][e] = 0.f;
    }
  };
  auto stage_x = [&](int t, int slot) {   // cvt + LDS ring + passthrough store
    #pragma unroll
    for (int d = 0; d < 4; ++d)
      xs[t & 3][d][lane] = pack_bf(xb[slot][d], xb[slot][d + 4]);
    float* po = out + OUT_X + xoff + t * NF;
    if (q < 2) {
      memcpy(po, &xb[slot][0], 16);
      memcpy(po + 4, &xb[slot][4], 16);
    } else if (q == 2) {
      po[0] = xb[slot][0];
    }
  };

  if (w == 0) {
    #pragma unroll
    for (int k = 0; k < 4; ++k) load_x(k, k);
    stage_x(0, 0);
  }
  __syncthreads();   // one full barrier: hx zeros, xs[0], weights in regs

  // ---- LDS pointers
  unsigned short* hw0[2]; unsigned short* hw1[2];
  const unsigned* hr[2];
  #pragma unroll
  for (int bf = 0; bf < 2; ++bf) {
    unsigned* p0 = &((unsigned*)hx)[bf * 260 + q * 65 + bb * 4 + (((w >> 1) + bb) & 3)];
    hw0[bf] = (unsigned short*)p0 + (w & 1);
    unsigned* p1 = &((unsigned*)hx)[bf * 260 + bb * 4 + ((2 + bb) & 3)];
    hw1[bf] = (unsigned short*)p1;   // j=16: plane 0, e=2, lo half
    hr[bf] = &((unsigned*)hx)[bf * 260 + bb * 4 + ((q + bb) & 3)];
  }

  float c0 = 0.f, c1 = 0.f, hA = 0.f, hB = 0.f;
  float* op0 = out + (b0 + bb) * L_SEQ * NF + (4 * w + q);
  float* op1 = out + (b0 + bb) * L_SEQ * NF + 16;

  for (int tb = 0; tb < L_SEQ; tb += 4) {
    #pragma unroll
    for (int k = 0; k < 4; ++k) {
      const int t = tb + k;
      // h fragment (critical path), then x fragment
      unsigned bhd[4], bxd[4];
      const unsigned* hrb = hr[t & 1];
      #pragma unroll
      for (int u = 0; u < 4; ++u) bhd[u] = hrb[u * 65];
      #pragma unroll
      for (int d = 0; d < 4; ++d) bxd[d] = ((const unsigned*)xs)[(t & 3) * 256 + d * 64 + lane];
      bf16x8 bh = __builtin_bit_cast(bf16x8, i32x4{(int)bhd[0], (int)bhd[1], (int)bhd[2], (int)bhd[3]});
      bf16x8 bx = __builtin_bit_cast(bf16x8, i32x4{(int)bxd[0], (int)bxd[1], (int)bxd[2], (int)bxd[3]});

      f32x4 acc0 = __builtin_amdgcn_mfma_f32_16x16x32_bf16(a0[0], bx, bias[0], 0, 0, 0);
      acc0       = __builtin_amdgcn_mfma_f32_16x16x32_bf16(a1[0], bh, acc0,    0, 0, 0);
      f32x4 acc1;
      if (w == 3) {
        acc1 = __builtin_amdgcn_mfma_f32_16x16x32_bf16(a0[1], bx, bias[1], 0, 0, 0);
        acc1 = __builtin_amdgcn_mfma_f32_16x16x32_bf16(a1[1], bh, acc1,    0, 0, 0);
      }

      { // tile tt0: j = 4w+q, all lanes valid
        float gi = sigm(acc0[0]), gf = sigm(acc0[1]);
        float gg = tanh_f(acc0[2]), go = sigm(acc0[3]);
        c0 = gf * c0 + gi * gg;
        hA = go * tanh_f(c0);
        *hw0[(t + 1) & 1] = bf1(hA);     // LDS first (critical), store after
        op0[t * NF] = hA;
      }
      if (w == 3) { // tile 4: j=16 valid only at q==0
        float gi = sigm(acc1[0]), gf = sigm(acc1[1]);
        float gg = tanh_f(acc1[2]), go = sigm(acc1[3]);
        c1 = gf * c1 + gi * gg;
        hB = go * tanh_f(c1);
        if (q == 0) {
          *hw1[(t + 1) & 1] = bf1(hB);
          op1[t * NF] = hB;
        }
      }
      if (w == 0) {
        if (t + 1 < L_SEQ) stage_x(t + 1, (t + 1) & 3);
        if (t + 4 < L_SEQ) load_x(t & 3, t + 4);
      }
      // LDS-only barrier: do NOT drain vmcnt (global stores have no in-kernel reader)
      asm volatile("s_waitcnt lgkmcnt(0)\n\ts_barrier" ::: "memory");
    }
  }

  // final (h, c)
  {
    const int jf = 4 * w + q;
    out[OUT_H + (b0 + bb) * NF + jf] = hA;
    out[OUT_C + (b0 + bb) * NF + jf] = c0;
    if (w == 3 && q == 0) {
      out[OUT_H + (b0 + bb) * NF + 16] = hB;
      out[OUT_C + (b0 + bb) * NF + 16] = c1;
    }
  }
}

extern "C" void kernel_launch(void* const* d_in, const int* in_sizes, int n_in,
                              void* d_out, int out_size, void* d_ws, size_t ws_size,
                              hipStream_t stream) {
  (void)in_sizes; (void)n_in; (void)out_size; (void)d_ws; (void)ws_size;
  const float* x    = (const float*)d_in[0];
  const float* W_ih = (const float*)d_in[1];
  const float* W_hh = (const float*)d_in[2];
  const float* b_ih = (const float*)d_in[3];
  const float* b_hh = (const float*)d_in[4];
  float* out = (float*)d_out;
  hipLaunchKernelGGL(lstm_kernel, dim3(B_TOT / 16), dim3(256), 0, stream,
                     x, W_ih, W_hh, b_ih, b_hh, out);
}